// Round 6
// baseline (371.742 us; speedup 1.0000x reference)
//
#include <hip/hip_runtime.h>
#include <hip/hip_bf16.h>
#include <stdint.h>

#define VOCAB 10000
#define XDIM 128
#define HID 256
#define BATCH 128
#define SEQ 50
#define ROWS (BATCH * SEQ) /* 6400 */

// K3 tiling
#define BM 128
#define BN 256
#define BK 32              /* double-buffered K-step */
#define NKT (HID / BK)     /* 8 K-steps */
#define NTM 50 /* 6400/128 */
#define NTN 40 /* ceil(10000/256) */

typedef __bf16 bf16x8 __attribute__((ext_vector_type(8)));
typedef float f32x4 __attribute__((ext_vector_type(4)));

__device__ __forceinline__ uint16_t f2bf(float f) {
    union { float f; uint32_t i; } v;
    v.f = f;
    uint32_t x = v.i;
    return (uint16_t)((x + 0x7fffu + ((x >> 16) & 1u)) >> 16); // RNE
}

// ---------------------------------------------------------------------------
// K0: cast W_aff (fp32) -> bf16 into workspace. 2.56M elems, 8/thread.
// ---------------------------------------------------------------------------
__global__ __launch_bounds__(256) void k0_cast(
    const float* __restrict__ src, uint16_t* __restrict__ dst) {
    const int i = (blockIdx.x * 256 + threadIdx.x) * 8;
    float4 a = *(const float4*)(src + i);
    float4 b = *(const float4*)(src + i + 4);
    uint16_t t[8];
    t[0] = f2bf(a.x); t[1] = f2bf(a.y); t[2] = f2bf(a.z); t[3] = f2bf(a.w);
    t[4] = f2bf(b.x); t[5] = f2bf(b.y); t[6] = f2bf(b.z); t[7] = f2bf(b.w);
    *(uint4*)(dst + i) = *(const uint4*)t;
}

// ---------------------------------------------------------------------------
// K1: xin[r][j] = dot(emb[x[r]], W_ih[j]) + b_ih[j] + b_hh[j]   (fp32)
// (unchanged)
// ---------------------------------------------------------------------------
__global__ __launch_bounds__(256, 2) void k1_xin(
    const int* __restrict__ x, const float* __restrict__ emb,
    const float* __restrict__ Wih, const float* __restrict__ bih,
    const float* __restrict__ bhh, float* __restrict__ xin) {
    __shared__ __align__(16) float es[8][XDIM];
    const int r0 = blockIdx.x * 8;
    const int tid = threadIdx.x;

    {   // stage 8 emb rows: 256 threads x 4 floats
        const int row = tid >> 5, c = tid & 31;
        const int tok = x[r0 + row];
        *(float4*)&es[row][c * 4] = *(const float4*)(emb + tok * XDIM + c * 4);
    }
    __syncthreads();

    const int j = tid;
    float wf[XDIM];
    const float4* wrow = (const float4*)(Wih + j * XDIM);
#pragma unroll
    for (int c = 0; c < 32; ++c) *(float4*)&wf[c * 4] = wrow[c];
    const float bias = bih[j] + bhh[j];

    float acc[8];
#pragma unroll
    for (int r = 0; r < 8; ++r) acc[r] = bias;
#pragma unroll
    for (int k4 = 0; k4 < 32; ++k4) {
#pragma unroll
        for (int r = 0; r < 8; ++r) {
            float4 e = *(const float4*)&es[r][k4 * 4];
            acc[r] += e.x * wf[k4 * 4 + 0] + e.y * wf[k4 * 4 + 1] +
                      e.z * wf[k4 * 4 + 2] + e.w * wf[k4 * 4 + 3];
        }
    }
#pragma unroll
    for (int r = 0; r < 8; ++r) xin[(r0 + r) * HID + j] = acc[r];
}

// ---------------------------------------------------------------------------
// K2v3: recurrence, split-K. (unchanged)
// ---------------------------------------------------------------------------
__global__ __launch_bounds__(512, 2) void k2_rnn(
    const float* __restrict__ xin, const float* __restrict__ Whh,
    uint16_t* __restrict__ hs) {
    __shared__ __align__(16) float hb[HID];
    __shared__ float ps[HID];
    const int b = blockIdx.x;
    const int j = threadIdx.x & 255;
    const int half = threadIdx.x >> 8;

    float wh[128];
    const float4* wrow = (const float4*)(Whh + j * HID + half * 128);
#pragma unroll
    for (int c = 0; c < 32; ++c) *(float4*)&wh[c * 4] = wrow[c];

    if (threadIdx.x < HID) hb[threadIdx.x] = 0.0f;
    __syncthreads();

    const float* xr = xin + b * SEQ * HID;
    uint16_t* hr = hs + b * SEQ * HID;

    for (int t = 0; t < SEQ; ++t) {
        const float xv = xr[t * HID + j];   // only half 0 uses; overlap latency
        const float4* h4 = (const float4*)(hb + half * 128);
        float a0 = 0.f, a1 = 0.f, a2 = 0.f, a3 = 0.f;
#pragma unroll
        for (int c = 0; c < 32; ++c) {
            float4 v = h4[c];
            a0 += v.x * wh[c * 4 + 0];
            a1 += v.y * wh[c * 4 + 1];
            a2 += v.z * wh[c * 4 + 2];
            a3 += v.w * wh[c * 4 + 3];
        }
        const float part = (a0 + a1) + (a2 + a3);
        if (half) ps[j] = part;
        __syncthreads();                    // ps visible; all hb reads done
        if (!half) {
            const float hn = tanhf(part + ps[j] + xv);
            hb[j] = hn;
            hr[t * HID + j] = f2bf(hn);
        }
        __syncthreads();                    // new hb visible
    }
}

// ---------------------------------------------------------------------------
// K3v6: double-buffered staged MFMA loop (T3-minimum 2-phase) + LDS nt
// epilogue. v5 (88µs) paid a cold stage + vmcnt(0) drain + 2 barriers per
// K-step (stage not overlapped with MFMA). v6: BK=32, two LDS buffers
// (2x8KB A + 2x16KB B = 48KB, same as v5 -> up to 3 blocks/CU); per K-step:
// issue next tile's global_load_lds FIRST, then ds_read+MFMA current tile,
// then ONE __syncthreads (its vmcnt(0) drain is short: loads had ~full MFMA
// phase in flight). Swizzle for BK=32 rows (4 granules): slot=gk^((R>>1)&3),
// source perm gsw=((ln&3)^((ln>>3)&3))*8 -> 16 lanes hit 8 distinct 16B
// positions x2 lanes = 2-way alias (free). Epilogue as v5 (aliases smem).
// ---------------------------------------------------------------------------
__global__ __launch_bounds__(256, 2) void k3_gemm(
    const uint16_t* __restrict__ A,   // hs  [6400][256] bf16
    const uint16_t* __restrict__ Bw,  // W_aff [10000][256] bf16
    const float* __restrict__ baff,   // [10000] fp32
    float* __restrict__ out) {
    __shared__ __align__(16) char smem[49152];          // 48 KB
    uint16_t* As = (uint16_t*)smem;                     // [2][BM*BK] 2x8 KB
    uint16_t* Bs = (uint16_t*)(smem + 2 * BM * BK * 2); // [2][BN*BK] 2x16 KB

    // XCD swizzle: hw XCD = bid0 % 8; give each XCD a contiguous work chunk
    const int bid0 = blockIdx.x;
    const int bid = (bid0 & 7) * ((NTM * NTN) / 8) + (bid0 >> 3);
    const int bm = bid % NTM, bn = bid / NTM;  // consecutive work shares bn
    const int m0 = bm * BM, n0 = bn * BN;
    const int tid = threadIdx.x;
    const int wv = tid >> 6, ln = tid & 63;
    const int wm = wv & 1, wn = wv >> 1;   // 2x2 wave grid: 64 x 128 per wave
    const int quad = ln >> 4, l15 = ln & 15;

    f32x4 acc[4][8];
#pragma unroll
    for (int i = 0; i < 4; ++i)
#pragma unroll
        for (int jj = 0; jj < 8; ++jj) acc[i][jj] = (f32x4)0.0f;

    // staging geometry: 1KB chunk = 16 rows x 32 elems; lane -> row ln>>2,
    // slot ln&3; source granule = slot ^ ((row>>1)&3)
    const int lrow = ln >> 2;                        // 0..15
    const int gsw = ((ln & 3) ^ ((ln >> 3) & 3)) * 8; // swizzled src granule

    // clamp B rows once (A rows always in range)
    int bnrow[4];
#pragma unroll
    for (int i = 0; i < 4; ++i) {
        int n = n0 + (wv * 4 + i) * 16 + lrow;
        bnrow[i] = n > VOCAB - 1 ? VOCAB - 1 : n;
    }

#define STAGE(kt, buf)                                                        \
    do {                                                                      \
        const int k0_ = (kt) * BK;                                            \
        uint16_t* Asb_ = As + (buf) * (BM * BK);                              \
        uint16_t* Bsb_ = Bs + (buf) * (BN * BK);                              \
        _Pragma("unroll")                                                     \
        for (int i_ = 0; i_ < 2; ++i_) {                                      \
            const int ci_ = wv * 2 + i_;                                      \
            const uint16_t* g_ =                                              \
                A + (size_t)(m0 + ci_ * 16 + lrow) * HID + k0_ + gsw;         \
            __builtin_amdgcn_global_load_lds(                                 \
                (const __attribute__((address_space(1))) void*)g_,            \
                (__attribute__((address_space(3))) void*)(Asb_ + ci_ * 512),  \
                16, 0, 0);                                                    \
        }                                                                     \
        _Pragma("unroll")                                                     \
        for (int i_ = 0; i_ < 4; ++i_) {                                      \
            const int ci_ = wv * 4 + i_;                                      \
            const uint16_t* g_ =                                              \
                Bw + (size_t)bnrow[i_] * HID + k0_ + gsw;                     \
            __builtin_amdgcn_global_load_lds(                                 \
                (const __attribute__((address_space(1))) void*)g_,            \
                (__attribute__((address_space(3))) void*)(Bsb_ + ci_ * 512),  \
                16, 0, 0);                                                    \
        }                                                                     \
    } while (0)

    STAGE(0, 0);
    __syncthreads();  // prologue drain

#pragma unroll
    for (int kt = 0; kt < NKT; ++kt) {
        const int cur = kt & 1;
        if (kt < NKT - 1) STAGE(kt + 1, cur ^ 1);  // overlap with MFMA below

        const uint16_t* Asb = As + cur * (BM * BK);
        const uint16_t* Bsb = Bs + cur * (BN * BK);
        bf16x8 af[4], bf[8];
#pragma unroll
        for (int tm = 0; tm < 4; ++tm) {
            const int R = wm * 64 + tm * 16 + l15;
            af[tm] = *(const bf16x8*)&Asb[R * 32 + ((quad ^ ((R >> 1) & 3)) * 8)];
        }
#pragma unroll
        for (int tn = 0; tn < 8; ++tn) {
            const int R = wn * 128 + tn * 16 + l15;
            bf[tn] = *(const bf16x8*)&Bsb[R * 32 + ((quad ^ ((R >> 1) & 3)) * 8)];
        }
#pragma unroll
        for (int tm = 0; tm < 4; ++tm)
#pragma unroll
            for (int tn = 0; tn < 8; ++tn)
                acc[tm][tn] = __builtin_amdgcn_mfma_f32_16x16x32_bf16(
                    af[tm], bf[tn], acc[tm][tn], 0, 0, 0);

        __syncthreads();  // one barrier/step: drains stage, fences LDS reuse
    }
#undef STAGE

    // epilogue: C fragment layout col = l15, row = quad*4 + r.
    // Stage per-wave 16x128 chunk in LDS (aliases As/Bs), read back
    // row-contiguous, nt-store 16B/lane = 512B contiguous per wave-store.
    float* csw = (float*)smem + wv * 16 * 132;   // per-wave [16][132], 33 KB tot
    float bias[8];
#pragma unroll
    for (int tn = 0; tn < 8; ++tn) {
        int n = n0 + wn * 128 + tn * 16 + l15;
        bias[tn] = baff[n > VOCAB - 1 ? VOCAB - 1 : n];
    }
#pragma unroll
    for (int tm = 0; tm < 4; ++tm) {
        // write fragments into LDS (bank = (quad*4r+l15) pattern: 2-way alias)
#pragma unroll
        for (int tn = 0; tn < 8; ++tn)
#pragma unroll
            for (int r = 0; r < 4; ++r)
                csw[(quad * 4 + r) * 132 + tn * 16 + l15] =
                    acc[tm][tn][r] + bias[tn];
        __syncthreads();
        // read back: 2 rows/iter, 32 lanes x f32x4 = 512B contiguous per row
#pragma unroll
        for (int it = 0; it < 8; ++it) {
            const int row = it * 2 + (ln >> 5);
            const int c4 = (ln & 31) * 4;
            const f32x4 v = *(const f32x4*)&csw[row * 132 + c4];
            const int gm = m0 + wm * 64 + tm * 16 + row;
            const int gn = n0 + wn * 128 + c4;
            if (gn < VOCAB)   // VOCAB%4==0: whole f32x4 valid or whole invalid
                __builtin_nontemporal_store(
                    v, (f32x4*)(out + (size_t)gm * VOCAB + gn));
        }
        __syncthreads();  // reads done before next tm overwrites
    }
}

extern "C" void kernel_launch(void* const* d_in, const int* in_sizes, int n_in,
                              void* d_out, int out_size, void* d_ws, size_t ws_size,
                              hipStream_t stream) {
    const int* x = (const int*)d_in[0];
    const float* emb = (const float*)d_in[1];
    const float* Wih = (const float*)d_in[2];
    const float* Whh = (const float*)d_in[3];
    const float* bih = (const float*)d_in[4];
    const float* bhh = (const float*)d_in[5];
    const float* Waff = (const float*)d_in[6];
    const float* baff = (const float*)d_in[7];

    float* xin = (float*)d_ws;                                         // 6.55 MB
    uint16_t* hsb = (uint16_t*)((char*)d_ws + (size_t)ROWS * HID * 4); // 3.28 MB
    uint16_t* Wb = hsb + (size_t)ROWS * HID;                           // 5.12 MB
    float* out = (float*)d_out;

    k0_cast<<<(VOCAB * HID) / (256 * 8), 256, 0, stream>>>(Waff, Wb);
    k1_xin<<<ROWS / 8, 256, 0, stream>>>(x, emb, Wih, bih, bhh, xin);
    k2_rnn<<<BATCH, 512, 0, stream>>>(xin, Whh, hsb);
    k3_gemm<<<NTM * NTN, 256, 0, stream>>>(hsb, Wb, baff, out);
}

// Round 7
// 360.280 us; speedup vs baseline: 1.0318x; 1.0318x over previous
//
#include <hip/hip_runtime.h>
#include <hip/hip_bf16.h>
#include <stdint.h>

#define VOCAB 10000
#define XDIM 128
#define HID 256
#define BATCH 128
#define SEQ 50
#define ROWS (BATCH * SEQ) /* 6400 */

// K3 tiling
#define BM 128
#define BN 256
#define BK 64
#define NTM 50 /* 6400/128 */
#define NTN 40 /* ceil(10000/256) */

// fused K0+K1 grid split
#define K1_BLOCKS (ROWS / 8)                 /* 800 */
#define K0_BLOCKS ((VOCAB * HID) / (256 * 8)) /* 1250 */

typedef __bf16 bf16x8 __attribute__((ext_vector_type(8)));
typedef float f32x4 __attribute__((ext_vector_type(4)));

__device__ __forceinline__ uint16_t f2bf(float f) {
    union { float f; uint32_t i; } v;
    v.f = f;
    uint32_t x = v.i;
    return (uint16_t)((x + 0x7fffu + ((x >> 16) & 1u)) >> 16); // RNE
}

// ---------------------------------------------------------------------------
// K01: fused W_aff cast (K0) + xin projection (K1). The two are
// data-independent; K1 blocks come FIRST so xin (K2's critical-path input)
// starts immediately and the cast fills otherwise-idle CUs in K1's shadow.
// Removes one kernel-launch boundary from the serial 4-kernel chain.
// ---------------------------------------------------------------------------
__global__ __launch_bounds__(256, 2) void k01_fused(
    const int* __restrict__ x, const float* __restrict__ emb,
    const float* __restrict__ Wih, const float* __restrict__ bih,
    const float* __restrict__ bhh, float* __restrict__ xin,
    const float* __restrict__ Waff, uint16_t* __restrict__ Wb) {
    __shared__ __align__(16) float es[8][XDIM];
    const int tid = threadIdx.x;

    if (blockIdx.x >= K1_BLOCKS) {
        // ---- K0 path: cast W_aff fp32 -> bf16, 8 elems/thread ----
        const int i = ((blockIdx.x - K1_BLOCKS) * 256 + tid) * 8;
        float4 a = *(const float4*)(Waff + i);
        float4 b = *(const float4*)(Waff + i + 4);
        uint16_t t[8];
        t[0] = f2bf(a.x); t[1] = f2bf(a.y); t[2] = f2bf(a.z); t[3] = f2bf(a.w);
        t[4] = f2bf(b.x); t[5] = f2bf(b.y); t[6] = f2bf(b.z); t[7] = f2bf(b.w);
        *(uint4*)(Wb + i) = *(const uint4*)t;
        return;
    }

    // ---- K1 path: xin[r][j] = dot(emb[x[r]], W_ih[j]) + b_ih[j] + b_hh[j]
    const int r0 = blockIdx.x * 8;
    {   // stage 8 emb rows: 256 threads x 4 floats
        const int row = tid >> 5, c = tid & 31;
        const int tok = x[r0 + row];
        *(float4*)&es[row][c * 4] = *(const float4*)(emb + tok * XDIM + c * 4);
    }
    __syncthreads();

    const int j = tid;
    float wf[XDIM];
    const float4* wrow = (const float4*)(Wih + j * XDIM);
#pragma unroll
    for (int c = 0; c < 32; ++c) *(float4*)&wf[c * 4] = wrow[c];
    const float bias = bih[j] + bhh[j];

    float acc[8];
#pragma unroll
    for (int r = 0; r < 8; ++r) acc[r] = bias;
#pragma unroll
    for (int k4 = 0; k4 < 32; ++k4) {
#pragma unroll
        for (int r = 0; r < 8; ++r) {
            float4 e = *(const float4*)&es[r][k4 * 4];
            acc[r] += e.x * wf[k4 * 4 + 0] + e.y * wf[k4 * 4 + 1] +
                      e.z * wf[k4 * 4 + 2] + e.w * wf[k4 * 4 + 3];
        }
    }
#pragma unroll
    for (int r = 0; r < 8; ++r) xin[(r0 + r) * HID + j] = acc[r];
}

// ---------------------------------------------------------------------------
// K2v3: recurrence, split-K. (unchanged)
// ---------------------------------------------------------------------------
__global__ __launch_bounds__(512, 2) void k2_rnn(
    const float* __restrict__ xin, const float* __restrict__ Whh,
    uint16_t* __restrict__ hs) {
    __shared__ __align__(16) float hb[HID];
    __shared__ float ps[HID];
    const int b = blockIdx.x;
    const int j = threadIdx.x & 255;
    const int half = threadIdx.x >> 8;

    float wh[128];
    const float4* wrow = (const float4*)(Whh + j * HID + half * 128);
#pragma unroll
    for (int c = 0; c < 32; ++c) *(float4*)&wh[c * 4] = wrow[c];

    if (threadIdx.x < HID) hb[threadIdx.x] = 0.0f;
    __syncthreads();

    const float* xr = xin + b * SEQ * HID;
    uint16_t* hr = hs + b * SEQ * HID;

    for (int t = 0; t < SEQ; ++t) {
        const float xv = xr[t * HID + j];   // only half 0 uses; overlap latency
        const float4* h4 = (const float4*)(hb + half * 128);
        float a0 = 0.f, a1 = 0.f, a2 = 0.f, a3 = 0.f;
#pragma unroll
        for (int c = 0; c < 32; ++c) {
            float4 v = h4[c];
            a0 += v.x * wh[c * 4 + 0];
            a1 += v.y * wh[c * 4 + 1];
            a2 += v.z * wh[c * 4 + 2];
            a3 += v.w * wh[c * 4 + 3];
        }
        const float part = (a0 + a1) + (a2 + a3);
        if (half) ps[j] = part;
        __syncthreads();                    // ps visible; all hb reads done
        if (!half) {
            const float hn = tanhf(part + ps[j] + xv);
            hb[j] = hn;
            hr[t * HID + j] = f2bf(hn);
        }
        __syncthreads();                    // new hb visible
    }
}

// ---------------------------------------------------------------------------
// K3v5 (reverted from v6): staged main loop (global_load_lds width-16 + XOR
// swizzled LDS fragment reads, 2-barrier 4x BK=64) + LDS-transposed nt
// epilogue. Measured: v5 ~88µs; v6 dbuf BK=32 regressed to ~96µs (compiler
// drains vmcnt(0) at every barrier regardless — m99/m131 pattern). Keep v5.
// ---------------------------------------------------------------------------
__global__ __launch_bounds__(256, 2) void k3_gemm(
    const uint16_t* __restrict__ A,   // hs  [6400][256] bf16
    const uint16_t* __restrict__ Bw,  // W_aff [10000][256] bf16
    const float* __restrict__ baff,   // [10000] fp32
    float* __restrict__ out) {
    __shared__ __align__(16) char smem[49152];       // 48 KB
    uint16_t* As = (uint16_t*)smem;                  // [BM*BK] 16 KB
    uint16_t* Bs = (uint16_t*)(smem + BM * BK * 2);  // [BN*BK] 32 KB

    // XCD swizzle: hw XCD = bid0 % 8; give each XCD a contiguous work chunk
    const int bid0 = blockIdx.x;
    const int bid = (bid0 & 7) * ((NTM * NTN) / 8) + (bid0 >> 3);
    const int bm = bid % NTM, bn = bid / NTM;  // consecutive work shares bn
    const int m0 = bm * BM, n0 = bn * BN;
    const int tid = threadIdx.x;
    const int wv = tid >> 6, ln = tid & 63;
    const int wm = wv & 1, wn = wv >> 1;   // 2x2 wave grid: 64 x 128 per wave
    const int quad = ln >> 4, l15 = ln & 15;

    f32x4 acc[4][8];
#pragma unroll
    for (int i = 0; i < 4; ++i)
#pragma unroll
        for (int jj = 0; jj < 8; ++jj) acc[i][jj] = (f32x4)0.0f;

    const int lrow = ln >> 3;               // 0..7 row within 8-row chunk
    const int gsw = ((ln & 7) ^ lrow) * 8;  // swizzled source granule (elems)

    for (int kt = 0; kt < 4; ++kt) {
        const int k0 = kt * BK;
        // stage A: 16 chunks of 1 KiB; wave wv does 4
#pragma unroll
        for (int i = 0; i < 4; ++i) {
            const int ci = wv * 4 + i;
            const uint16_t* g = A + (size_t)(m0 + ci * 8 + lrow) * HID + k0 + gsw;
            __builtin_amdgcn_global_load_lds(
                (const __attribute__((address_space(1))) void*)g,
                (__attribute__((address_space(3))) void*)(As + ci * 512), 16, 0, 0);
        }
        // stage B: 32 chunks; wave wv does 8 (clamp OOB rows; stores guarded)
#pragma unroll
        for (int i = 0; i < 8; ++i) {
            const int ci = wv * 8 + i;
            int n = n0 + ci * 8 + lrow;
            if (n > VOCAB - 1) n = VOCAB - 1;
            const uint16_t* g = Bw + (size_t)n * HID + k0 + gsw;
            __builtin_amdgcn_global_load_lds(
                (const __attribute__((address_space(1))) void*)g,
                (__attribute__((address_space(3))) void*)(Bs + ci * 512), 16, 0, 0);
        }
        __syncthreads();  // vmcnt(0) drain + barrier

#pragma unroll
        for (int kk = 0; kk < 2; ++kk) {
            const int gk = kk * 4 + quad;   // k-granule index for this lane
            bf16x8 af[4], bf[8];
#pragma unroll
            for (int tm = 0; tm < 4; ++tm) {
                const int R = wm * 64 + tm * 16 + l15;
                af[tm] = *(const bf16x8*)&As[R * 64 + ((gk ^ (R & 7)) * 8)];
            }
#pragma unroll
            for (int tn = 0; tn < 8; ++tn) {
                const int R = wn * 128 + tn * 16 + l15;
                bf[tn] = *(const bf16x8*)&Bs[R * 64 + ((gk ^ (R & 7)) * 8)];
            }
#pragma unroll
            for (int tm = 0; tm < 4; ++tm)
#pragma unroll
                for (int tn = 0; tn < 8; ++tn)
                    acc[tm][tn] = __builtin_amdgcn_mfma_f32_16x16x32_bf16(
                        af[tm], bf[tn], acc[tm][tn], 0, 0, 0);
        }
        __syncthreads();  // all LDS reads drained (also guards epilogue alias)
    }

    // epilogue: C fragment layout col = l15, row = quad*4 + r.
    // Stage per-wave 16x128 chunk in LDS (aliases As/Bs), read back
    // row-contiguous, nt-store 16B/lane = 512B contiguous per wave-store.
    float* csw = (float*)smem + wv * 16 * 132;   // per-wave [16][132], 33 KB tot
    float bias[8];
#pragma unroll
    for (int tn = 0; tn < 8; ++tn) {
        int n = n0 + wn * 128 + tn * 16 + l15;
        bias[tn] = baff[n > VOCAB - 1 ? VOCAB - 1 : n];
    }
#pragma unroll
    for (int tm = 0; tm < 4; ++tm) {
        // write fragments into LDS (bank = (quad*16+l15)%32: 2-way alias=free)
#pragma unroll
        for (int tn = 0; tn < 8; ++tn)
#pragma unroll
            for (int r = 0; r < 4; ++r)
                csw[(quad * 4 + r) * 132 + tn * 16 + l15] =
                    acc[tm][tn][r] + bias[tn];
        __syncthreads();
        // read back: 2 rows/iter, 32 lanes x f32x4 = 512B contiguous per row
#pragma unroll
        for (int it = 0; it < 8; ++it) {
            const int row = it * 2 + (ln >> 5);
            const int c4 = (ln & 31) * 4;
            const f32x4 v = *(const f32x4*)&csw[row * 132 + c4];
            const int gm = m0 + wm * 64 + tm * 16 + row;
            const int gn = n0 + wn * 128 + c4;
            if (gn < VOCAB)   // VOCAB%4==0: whole f32x4 valid or whole invalid
                __builtin_nontemporal_store(
                    v, (f32x4*)(out + (size_t)gm * VOCAB + gn));
        }
        __syncthreads();  // reads done before next tm overwrites
    }
}

extern "C" void kernel_launch(void* const* d_in, const int* in_sizes, int n_in,
                              void* d_out, int out_size, void* d_ws, size_t ws_size,
                              hipStream_t stream) {
    const int* x = (const int*)d_in[0];
    const float* emb = (const float*)d_in[1];
    const float* Wih = (const float*)d_in[2];
    const float* Whh = (const float*)d_in[3];
    const float* bih = (const float*)d_in[4];
    const float* bhh = (const float*)d_in[5];
    const float* Waff = (const float*)d_in[6];
    const float* baff = (const float*)d_in[7];

    float* xin = (float*)d_ws;                                         // 6.55 MB
    uint16_t* hsb = (uint16_t*)((char*)d_ws + (size_t)ROWS * HID * 4); // 3.28 MB
    uint16_t* Wb = hsb + (size_t)ROWS * HID;                           // 5.12 MB
    float* out = (float*)d_out;

    k01_fused<<<K1_BLOCKS + K0_BLOCKS, 256, 0, stream>>>(
        x, emb, Wih, bih, bhh, xin, Waff, Wb);
    k2_rnn<<<BATCH, 512, 0, stream>>>(xin, Whh, hsb);
    k3_gemm<<<NTM * NTN, 256, 0, stream>>>(hsb, Wb, baff, out);
}